// Round 9
// baseline (2065.970 us; speedup 1.0000x reference)
//
#include <hip/hip_runtime.h>
#include <hip/hip_bf16.h>
#include <math.h>

#define DIM 384
#define HEADS 12
#define HD 32
#define MLP_H 1536
#define BATCH 8
#define N1 256
#define N2 257
#define QP 1152          // fused qkv row pitch (shorts)
#define SCALE 0.17677669529663687f
#define TIME_SCALE 18.0f

typedef __attribute__((ext_vector_type(8))) short frag8;
typedef __attribute__((ext_vector_type(4))) float f32x4;

__device__ inline short f2bf(float x) {
    __hip_bfloat16 h = __float2bfloat16(x);
    short s;
    __builtin_memcpy(&s, &h, 2);
    return s;
}
__device__ inline float bf2f(short s) {
    unsigned u = ((unsigned)(unsigned short)s) << 16;
    float f;
    __builtin_memcpy(&f, &u, 4);
    return f;
}

// ------------------------------------------------------------------
// weight conversion: fp32 -> bf16 (plain)
// ------------------------------------------------------------------
__global__ __launch_bounds__(256) void conv_kernel(
        const float* __restrict__ in, short* __restrict__ out, int n) {
    int i = (blockIdx.x * 256 + threadIdx.x) * 4;
    if (i >= n) return;
    float4 v = *(const float4*)(in + i);
    out[i]     = f2bf(v.x);
    out[i + 1] = f2bf(v.y);
    out[i + 2] = f2bf(v.z);
    out[i + 3] = f2bf(v.w);
}

// gather-convert: per layer pack [wq;wk;wv] -> (L,1152,384) bf16
__global__ __launch_bounds__(256) void conv_qkv_kernel(
        const float* __restrict__ wq, const float* __restrict__ wk,
        const float* __restrict__ wv, short* __restrict__ out, int L) {
    size_t idx = ((size_t)blockIdx.x * 256 + threadIdx.x) * 4;
    size_t total = (size_t)L * QP * DIM;
    if (idx >= total) return;
    size_t k = idx % DIM;
    size_t row = idx / DIM;
    size_t r = row % QP;
    size_t l = row / QP;
    int which = (int)(r / DIM);
    int rr = (int)(r % DIM);
    const float* src = ((which == 0) ? wq : (which == 1) ? wk : wv)
                     + (l * DIM + rr) * DIM + k;
    float4 v = *(const float4*)src;
    out[idx]     = f2bf(v.x);
    out[idx + 1] = f2bf(v.y);
    out[idx + 2] = f2bf(v.z);
    out[idx + 3] = f2bf(v.w);
}

// ------------------------------------------------------------------
// rel bias -> bf16
// ------------------------------------------------------------------
__global__ __launch_bounds__(256) void rel_kernel(
        const float* __restrict__ x0, const float* __restrict__ w1d,
        const float* __restrict__ b1d, const float* __restrict__ wp,
        const float* __restrict__ bp, short* __restrict__ rel) {
    __shared__ float swp[HD * HD];
    __shared__ float sbp[HD];
    __shared__ float sw1[8];
    __shared__ float sb1;
    __shared__ float sfreq[16];
    int tid = threadIdx.x;
    for (int i = tid; i < HD * HD; i += 256) swp[i] = wp[i];
    if (tid < HD) sbp[tid] = bp[tid];
    if (tid < 8) sw1[tid] = w1d[tid];
    if (tid == 0) sb1 = b1d[0];
    if (tid < 16) sfreq[tid] = expf(-(float)tid * 0.5756462732485114f);
    __syncthreads();

    int gid = blockIdx.x * 256 + tid;
    int j  = gid & (N1 - 1);
    int bi = gid >> 8;
    int i  = bi & (N1 - 1);
    int b  = bi >> 8;

    const float* pi = x0 + (size_t)(b * N1 + i) * 4;
    const float* pj = x0 + (size_t)(b * N1 + j) * 4;
    float dx = pi[0] - pj[0], dy = pi[1] - pj[1], dz = pi[2] - pj[2];
    float dt = pi[3] - pj[3] * TIME_SCALE;
    float dx2 = dx * dx, dy2 = dy * dy, dz2 = dz * dz, dt2 = dt * dt;
    float ds2 = dx2 + dy2 + dz2 - dt2;
    float d = copysignf(sqrtf(fabsf(ds2)), ds2);
    d += dx * sw1[0] + dy * sw1[1] + dz * sw1[2] + dt * sw1[3]
       + dx2 * sw1[4] + dy2 * sw1[5] + dz2 * sw1[6] + dt2 * sw1[7] + sb1;
    d = fminf(fmaxf(d, -4.f), 4.f) * 1024.f;

    float emb[32];
    #pragma unroll
    for (int k = 0; k < 16; k++) {
        float s, c;
        sincosf(d * sfreq[k], &s, &c);
        emb[k] = s; emb[16 + k] = c;
    }
    short* out = rel + (size_t)gid * HD;
    #pragma unroll 4
    for (int c = 0; c < HD; c++) {
        float a = sbp[c];
        #pragma unroll
        for (int k = 0; k < 32; k++) a += emb[k] * swp[c * 32 + k];
        out[c] = f2bf(a);
    }
}

// ------------------------------------------------------------------
// LN-fused bf16 MFMA GEMM (K = 384 only): C = act(LN(A).W^T [+bias])
// A fp32 trunk row-major; LN computed in-block (stats pass + normalize
// into resident fragment-major A-tile), then 3 x BK=128 MFMA chunks
// with B-only staging + register prefetch. 512 thr, K-split reduce.
// do_gelu: 0 -> plain bf16 out, 1 -> bias+GELU bf16 out.
// ------------------------------------------------------------------
__global__ __launch_bounds__(512) void gemm_ln_bf16_kernel(
        const float* __restrict__ Af, const float* __restrict__ gamma,
        const float* __restrict__ beta, const short* __restrict__ W,
        const float* __restrict__ bias, short* __restrict__ Cb,
        int M, int Np, int do_gelu) {
    __shared__ short As3[3][2][2][4][64][8];   // 48 KB [chunk][kh][ks][q][row][e]
    __shared__ short Bs[2][2][4][64][8];       // 16 KB (one 128-chunk)
    __shared__ float gs[384], bs[384];
    __shared__ float psum[64][9], psq[64][9];
    int tid = threadIdx.x;
    int w = tid >> 6, lane = tid & 63;
    int nlo = lane & 15, quad = lane >> 4;
    int gq = w >> 2, wl = w & 3;
    int wm = wl >> 1, wn = wl & 1;
    int n0 = blockIdx.x * 64, m0 = blockIdx.y * 64;

    if (tid < 384) { gs[tid] = gamma[tid]; bs[tid] = beta[tid]; }

    int row = tid >> 3, seg = tid & 7;
    int gm = m0 + row;
    // ---- pass 1: per-row partial sums ----
    {
        float s = 0.f, s2 = 0.f;
        if (gm < M) {
            const float* src = Af + (size_t)gm * 384 + seg * 48;
            #pragma unroll
            for (int t = 0; t < 12; t++) {
                float4 v4 = *(const float4*)(src + t * 4);
                s += v4.x + v4.y + v4.z + v4.w;
                s2 += v4.x * v4.x + v4.y * v4.y + v4.z * v4.z + v4.w * v4.w;
            }
        }
        psum[row][seg] = s; psq[row][seg] = s2;
    }
    __syncthreads();
    float mean, rs;
    {
        float s = 0.f, s2 = 0.f;
        #pragma unroll
        for (int t = 0; t < 8; t++) { s += psum[row][t]; s2 += psq[row][t]; }
        mean = s * (1.f / 384.f);
        float var = s2 * (1.f / 384.f) - mean * mean;
        rs = rsqrtf(var + 1e-5f);
    }
    // ---- pass 2: normalize -> bf16 fragments (L1/L2-hot reload) ----
    {
        const frag8 fz = {0, 0, 0, 0, 0, 0, 0, 0};
        const float* src = Af + (size_t)gm * 384 + seg * 48;
        #pragma unroll
        for (int o = 0; o < 6; o++) {
            int kb = seg * 48 + o * 8;
            frag8 fv = fz;
            if (gm < M) {
                float4 va = *(const float4*)(src + o * 8);
                float4 vb = *(const float4*)(src + o * 8 + 4);
                fv[0] = f2bf((va.x - mean) * rs * gs[kb + 0] + bs[kb + 0]);
                fv[1] = f2bf((va.y - mean) * rs * gs[kb + 1] + bs[kb + 1]);
                fv[2] = f2bf((va.z - mean) * rs * gs[kb + 2] + bs[kb + 2]);
                fv[3] = f2bf((va.w - mean) * rs * gs[kb + 3] + bs[kb + 3]);
                fv[4] = f2bf((vb.x - mean) * rs * gs[kb + 4] + bs[kb + 4]);
                fv[5] = f2bf((vb.y - mean) * rs * gs[kb + 5] + bs[kb + 5]);
                fv[6] = f2bf((vb.z - mean) * rs * gs[kb + 6] + bs[kb + 6]);
                fv[7] = f2bf((vb.w - mean) * rs * gs[kb + 7] + bs[kb + 7]);
            }
            int oct = (kb & 127) >> 3;
            *(frag8*)&As3[kb >> 7][oct >> 3][(oct & 7) >> 2][oct & 3][row][0] = fv;
        }
    }

    // ---- main loop: B staging + MFMA ----
    int oct16 = tid & 15, rb = tid >> 4;
    int kh_s = oct16 >> 3, oo = oct16 & 7, ks_s = oo >> 2, q_s = oo & 3;
    frag8 pb0 = *(const frag8*)(W + (size_t)(n0 + rb) * 384 + oct16 * 8);
    frag8 pb1 = *(const frag8*)(W + (size_t)(n0 + rb + 32) * 384 + oct16 * 8);

    f32x4 acc00 = {0.f, 0.f, 0.f, 0.f}, acc01 = {0.f, 0.f, 0.f, 0.f};
    f32x4 acc10 = {0.f, 0.f, 0.f, 0.f}, acc11 = {0.f, 0.f, 0.f, 0.f};

    __syncthreads();   // A fragments + first B regs ready
    for (int c = 0; c < 3; c++) {
        *(frag8*)&Bs[kh_s][ks_s][q_s][rb][0]      = pb0;
        *(frag8*)&Bs[kh_s][ks_s][q_s][rb + 32][0] = pb1;
        __syncthreads();
        if (c < 2) {
            pb0 = *(const frag8*)(W + (size_t)(n0 + rb) * 384 + (c + 1) * 128 + oct16 * 8);
            pb1 = *(const frag8*)(W + (size_t)(n0 + rb + 32) * 384 + (c + 1) * 128 + oct16 * 8);
        }
        #pragma unroll
        for (int ks = 0; ks < 2; ks++) {
            frag8 a0 = *(const frag8*)&As3[c][gq][ks][quad][wm * 32 + nlo][0];
            frag8 a1 = *(const frag8*)&As3[c][gq][ks][quad][wm * 32 + 16 + nlo][0];
            frag8 b0 = *(const frag8*)&Bs[gq][ks][quad][wn * 32 + nlo][0];
            frag8 b1 = *(const frag8*)&Bs[gq][ks][quad][wn * 32 + 16 + nlo][0];
            acc00 = __builtin_amdgcn_mfma_f32_16x16x32_bf16(a0, b0, acc00, 0, 0, 0);
            acc01 = __builtin_amdgcn_mfma_f32_16x16x32_bf16(a0, b1, acc01, 0, 0, 0);
            acc10 = __builtin_amdgcn_mfma_f32_16x16x32_bf16(a1, b0, acc10, 0, 0, 0);
            acc11 = __builtin_amdgcn_mfma_f32_16x16x32_bf16(a1, b1, acc11, 0, 0, 0);
        }
        __syncthreads();
    }

    // ---- combine K-split partials (reuse Bs as f32x4 buffer) ----
    f32x4* red4 = (f32x4*)&Bs[0][0][0][0][0];
    int roff = wl * 64 + lane;
    if (gq == 1) {
        red4[roff]       = acc00;
        red4[256 + roff] = acc01;
        red4[512 + roff] = acc10;
        red4[768 + roff] = acc11;
    }
    __syncthreads();
    if (gq == 1) return;
    {
        f32x4 t0 = red4[roff], t1 = red4[256 + roff];
        f32x4 t2 = red4[512 + roff], t3 = red4[768 + roff];
        #pragma unroll
        for (int r = 0; r < 4; r++) {
            acc00[r] += t0[r]; acc01[r] += t1[r];
            acc10[r] += t2[r]; acc11[r] += t3[r];
        }
    }

    #pragma unroll
    for (int mi = 0; mi < 2; mi++) {
        #pragma unroll
        for (int nf = 0; nf < 2; nf++) {
            f32x4 av = (mi == 0) ? ((nf == 0) ? acc00 : acc01)
                                 : ((nf == 0) ? acc10 : acc11);
            int col = n0 + wn * 32 + nf * 16 + nlo;
            float bcol = bias ? bias[col] : 0.f;
            #pragma unroll
            for (int r = 0; r < 4; r++) {
                int orow = m0 + wm * 32 + mi * 16 + quad * 4 + r;
                if (orow >= M) continue;
                float v = av[r] + bcol;
                if (do_gelu) v = 0.5f * v * (1.f + erff(v * 0.70710678118654752f));
                Cb[(size_t)orow * Np + col] = f2bf(v);
            }
        }
    }
}

// ------------------------------------------------------------------
// bf16 MFMA GEMM v2 (verified R8) — O-proj / MLP2 (mode 2 epilogue)
// ------------------------------------------------------------------
__global__ __launch_bounds__(512) void gemm_bf16_kernel(
        const short* __restrict__ A, const short* __restrict__ W,
        const float* __restrict__ bias, const float* __restrict__ resid,
        const float* __restrict__ gvec, float* __restrict__ Cf,
        short* __restrict__ Cb, int M, int Np, int K, int mode) {
    __shared__ short As2[2][2][4][64][8];
    __shared__ short Bs2[2][2][4][64][8];
    int tid = threadIdx.x;
    int w = tid >> 6, lane = tid & 63;
    int nlo = lane & 15, quad = lane >> 4;
    int g = w >> 2, wl = w & 3;
    int wm = wl >> 1, wn = wl & 1;
    int n0 = blockIdx.x * 64, m0 = blockIdx.y * 64;

    f32x4 acc00 = {0.f, 0.f, 0.f, 0.f}, acc01 = {0.f, 0.f, 0.f, 0.f};
    f32x4 acc10 = {0.f, 0.f, 0.f, 0.f}, acc11 = {0.f, 0.f, 0.f, 0.f};

    int oct16 = tid & 15, rbase = tid >> 4;
    int kh_s = oct16 >> 3, oo = oct16 & 7, ks_s = oo >> 2, q_s = oo & 3;
    const frag8 fz = {0, 0, 0, 0, 0, 0, 0, 0};
    frag8 pa0 = fz, pa1 = fz, pb0, pb1;

    {
        int gm0 = m0 + rbase, gm1 = m0 + rbase + 32;
        if (gm0 < M) pa0 = *(const frag8*)(A + (size_t)gm0 * K + oct16 * 8);
        if (gm1 < M) pa1 = *(const frag8*)(A + (size_t)gm1 * K + oct16 * 8);
        pb0 = *(const frag8*)(W + (size_t)(n0 + rbase) * K + oct16 * 8);
        pb1 = *(const frag8*)(W + (size_t)(n0 + rbase + 32) * K + oct16 * 8);
    }

    for (int k0 = 0; k0 < K; k0 += 128) {
        *(frag8*)&As2[kh_s][ks_s][q_s][rbase][0]      = pa0;
        *(frag8*)&As2[kh_s][ks_s][q_s][rbase + 32][0] = pa1;
        *(frag8*)&Bs2[kh_s][ks_s][q_s][rbase][0]      = pb0;
        *(frag8*)&Bs2[kh_s][ks_s][q_s][rbase + 32][0] = pb1;
        __syncthreads();
        int kn = k0 + 128;
        if (kn < K) {
            int gm0 = m0 + rbase, gm1 = m0 + rbase + 32;
            pa0 = fz; pa1 = fz;
            if (gm0 < M) pa0 = *(const frag8*)(A + (size_t)gm0 * K + kn + oct16 * 8);
            if (gm1 < M) pa1 = *(const frag8*)(A + (size_t)gm1 * K + kn + oct16 * 8);
            pb0 = *(const frag8*)(W + (size_t)(n0 + rbase) * K + kn + oct16 * 8);
            pb1 = *(const frag8*)(W + (size_t)(n0 + rbase + 32) * K + kn + oct16 * 8);
        }
        #pragma unroll
        for (int ks = 0; ks < 2; ks++) {
            frag8 a0 = *(const frag8*)&As2[g][ks][quad][wm * 32 + nlo][0];
            frag8 a1 = *(const frag8*)&As2[g][ks][quad][wm * 32 + 16 + nlo][0];
            frag8 b0 = *(const frag8*)&Bs2[g][ks][quad][wn * 32 + nlo][0];
            frag8 b1 = *(const frag8*)&Bs2[g][ks][quad][wn * 32 + 16 + nlo][0];
            acc00 = __builtin_amdgcn_mfma_f32_16x16x32_bf16(a0, b0, acc00, 0, 0, 0);
            acc01 = __builtin_amdgcn_mfma_f32_16x16x32_bf16(a0, b1, acc01, 0, 0, 0);
            acc10 = __builtin_amdgcn_mfma_f32_16x16x32_bf16(a1, b0, acc10, 0, 0, 0);
            acc11 = __builtin_amdgcn_mfma_f32_16x16x32_bf16(a1, b1, acc11, 0, 0, 0);
        }
        __syncthreads();
    }

    f32x4* red4 = (f32x4*)&As2[0][0][0][0][0];
    int roff = wl * 64 + lane;
    if (g == 1) {
        red4[roff]       = acc00;
        red4[256 + roff] = acc01;
        red4[512 + roff] = acc10;
        red4[768 + roff] = acc11;
    }
    __syncthreads();
    if (g == 1) return;
    {
        f32x4 t0 = red4[roff], t1 = red4[256 + roff];
        f32x4 t2 = red4[512 + roff], t3 = red4[768 + roff];
        #pragma unroll
        for (int r = 0; r < 4; r++) {
            acc00[r] += t0[r]; acc01[r] += t1[r];
            acc10[r] += t2[r]; acc11[r] += t3[r];
        }
    }

    #pragma unroll
    for (int mi = 0; mi < 2; mi++) {
        #pragma unroll
        for (int nf = 0; nf < 2; nf++) {
            f32x4 av = (mi == 0) ? ((nf == 0) ? acc00 : acc01)
                                 : ((nf == 0) ? acc10 : acc11);
            int col = n0 + wn * 32 + nf * 16 + nlo;
            float bcol = (mode >= 1) ? bias[col] : 0.f;
            float gs = 1.f;
            if (mode == 2 && gvec) gs = gvec[col];
            #pragma unroll
            for (int r = 0; r < 4; r++) {
                int row = m0 + wm * 32 + mi * 16 + quad * 4 + r;
                if (row >= M) continue;
                float v = av[r] + bcol;
                if (mode == 1) v = 0.5f * v * (1.f + erff(v * 0.70710678118654752f));
                if (mode == 2) {
                    Cf[(size_t)row * Np + col] = resid[(size_t)row * Np + col] + gs * v;
                } else {
                    Cb[(size_t)row * Np + col] = f2bf(v);
                }
            }
        }
    }
}

// ------------------------------------------------------------------
// MFMA flash attention (no rel). Per-wave pbuf -> wave_barrier only
// (no workgroup barriers in the jb loop).
// ------------------------------------------------------------------
__global__ __launch_bounds__(256) void attn_mfma_kernel(
        const short* __restrict__ qkv, const float* __restrict__ maskv,
        short* __restrict__ ob, int Nseq) {
    __shared__ short kf[18][64][8];
    __shared__ short vf[9][2][64][8];
    __shared__ short pbuf[4][16][40];
    __shared__ float ms[320];

    int tid = threadIdx.x;
    int w = tid >> 6, lane = tid & 63;
    int n = lane & 15, quad = lane >> 4;
    int qg = blockIdx.x, h = blockIdx.y, b = blockIdx.z;
    size_t rowB = (size_t)(b * Nseq);

    for (int j = tid; j < 320; j += 256)
        ms[j] = (j < Nseq) ? maskv[b * Nseq + j] : 0.f;

    {
        int c0 = (tid & 3) * 8;
        for (int j = tid >> 2; j < 288; j += 64) {
            frag8 kk = {0, 0, 0, 0, 0, 0, 0, 0};
            frag8 vv = {0, 0, 0, 0, 0, 0, 0, 0};
            if (j < Nseq) {
                const short* base = qkv + (rowB + j) * QP + h * HD + c0;
                kk = *(const frag8*)(base + 384);
                vv = *(const frag8*)(base + 768);
            }
            *(frag8*)&kf[j >> 4][(c0 >> 3) * 16 + (j & 15)][0] = kk;
            #pragma unroll
            for (int e = 0; e < 8; e++) {
                int c = c0 + e;
                vf[j >> 5][c >> 4][((j & 31) >> 3) * 16 + (c & 15)][j & 7] = vv[e];
            }
        }
    }

    int i0 = qg * 64 + w * 16;
    frag8 qa = {0, 0, 0, 0, 0, 0, 0, 0};
    {
        int i = i0 + n;
        if (i < Nseq) qa = *(const frag8*)(qkv + (rowB + i) * QP + h * HD + quad * 8);
    }
    __syncthreads();

    float msq[4];
    #pragma unroll
    for (int r = 0; r < 4; r++) msq[r] = ms[i0 + quad * 4 + r];

    float mrow[4], lsum[4];
    #pragma unroll
    for (int r = 0; r < 4; r++) { mrow[r] = -3.0e38f; lsum[r] = 0.f; }
    f32x4 oacc0 = {0.f, 0.f, 0.f, 0.f}, oacc1 = {0.f, 0.f, 0.f, 0.f};

    for (int jb = 0; jb < 9; jb++) {
        frag8 kb0 = *(const frag8*)&kf[2 * jb][lane][0];
        frag8 kb1 = *(const frag8*)&kf[2 * jb + 1][lane][0];
        f32x4 z = {0.f, 0.f, 0.f, 0.f};
        f32x4 s0 = __builtin_amdgcn_mfma_f32_16x16x32_bf16(qa, kb0, z, 0, 0, 0);
        f32x4 s1 = __builtin_amdgcn_mfma_f32_16x16x32_bf16(qa, kb1, z, 0, 0, 0);

        int j0 = jb * 32 + n;
        int j1 = j0 + 16;
        float mj0 = ms[j0], mj1 = ms[j1];
        float pad0 = (j0 < Nseq) ? 0.f : -1e9f;
        float pad1 = (j1 < Nseq) ? 0.f : -1e9f;

        #pragma unroll
        for (int r = 0; r < 4; r++) {
            float mi = msq[r];
            float b0 = ((fmaxf(mi, mj0) < 0.f) ? 0.f : fminf(mi, mj0)) + pad0;
            float b1 = ((fmaxf(mi, mj1) < 0.f) ? 0.f : fminf(mi, mj1)) + pad1;
            float v0 = s0[r] * SCALE + b0;
            float v1 = s1[r] * SCALE + b1;
            float rm = fmaxf(v0, v1);
            rm = fmaxf(rm, __shfl_xor(rm, 1));
            rm = fmaxf(rm, __shfl_xor(rm, 2));
            rm = fmaxf(rm, __shfl_xor(rm, 4));
            rm = fmaxf(rm, __shfl_xor(rm, 8));
            float mn = fmaxf(mrow[r], rm);
            float alpha = __expf(mrow[r] - mn);
            mrow[r] = mn;
            float p0 = __expf(v0 - mn);
            float p1 = __expf(v1 - mn);
            float ps = p0 + p1;
            ps += __shfl_xor(ps, 1);
            ps += __shfl_xor(ps, 2);
            ps += __shfl_xor(ps, 4);
            ps += __shfl_xor(ps, 8);
            lsum[r] = lsum[r] * alpha + ps;
            oacc0[r] *= alpha;
            oacc1[r] *= alpha;
            pbuf[w][quad * 4 + r][n]      = f2bf(p0);
            pbuf[w][quad * 4 + r][n + 16] = f2bf(p1);
        }
        __builtin_amdgcn_wave_barrier();   // order pbuf writes before reads (per-wave)
        frag8 pa = *(const frag8*)&pbuf[w][n][quad * 8];
        frag8 vb0 = *(const frag8*)&vf[jb][0][lane][0];
        frag8 vb1 = *(const frag8*)&vf[jb][1][lane][0];
        oacc0 = __builtin_amdgcn_mfma_f32_16x16x32_bf16(pa, vb0, oacc0, 0, 0, 0);
        oacc1 = __builtin_amdgcn_mfma_f32_16x16x32_bf16(pa, vb1, oacc1, 0, 0, 0);
        __builtin_amdgcn_wave_barrier();   // order pbuf reads before next-iter writes
    }

    #pragma unroll
    for (int r = 0; r < 4; r++) {
        int i = i0 + quad * 4 + r;
        if (i < Nseq) {
            float invl = 1.f / lsum[r];
            ob[(rowB + i) * DIM + h * HD + n]      = f2bf(oacc0[r] * invl);
            ob[(rowB + i) * DIM + h * HD + 16 + n] = f2bf(oacc1[r] * invl);
        }
    }
}

// ------------------------------------------------------------------
// MFMA flash attention WITH rel bias (layer 0). Per-wave LDS only in
// the jb loop -> wave_barrier, no workgroup barriers.
// ------------------------------------------------------------------
__global__ __launch_bounds__(256) void attn_rel_mfma_kernel(
        const short* __restrict__ qkv, const short* __restrict__ relb,
        const float* __restrict__ maskv, short* __restrict__ ob) {
    const int Nseq = N1;
    __shared__ short kf[16][64][8];
    __shared__ short vf[8][2][64][8];
    __shared__ short pbuf[4][16][40];
    __shared__ float qrow[4][16][32];
    __shared__ float orel[4][16][33];
    __shared__ float alphas[4][16];
    __shared__ float ms[256];

    int tid = threadIdx.x;
    int w = tid >> 6, lane = tid & 63;
    int n = lane & 15, quad = lane >> 4;
    int qg = blockIdx.x, h = blockIdx.y, b = blockIdx.z;
    size_t rowB = (size_t)(b * Nseq);

    if (tid < 256) ms[tid] = maskv[b * Nseq + tid];

    {
        int c0 = (tid & 3) * 8;
        for (int j = tid >> 2; j < 256; j += 64) {
            const short* base = qkv + (rowB + j) * QP + h * HD + c0;
            frag8 kk = *(const frag8*)(base + 384);
            frag8 vv = *(const frag8*)(base + 768);
            *(frag8*)&kf[j >> 4][(c0 >> 3) * 16 + (j & 15)][0] = kk;
            #pragma unroll
            for (int e = 0; e < 8; e++) {
                int c = c0 + e;
                vf[j >> 5][c >> 4][((j & 31) >> 3) * 16 + (c & 15)][j & 7] = vv[e];
            }
        }
    }

    int i0 = qg * 64 + w * 16;
    frag8 qa = *(const frag8*)(qkv + (rowB + i0 + n) * QP + h * HD + quad * 8);
    {
        int il = lane >> 2, c8 = (lane & 3) * 8;
        frag8 qv = *(const frag8*)(qkv + (rowB + i0 + il) * QP + h * HD + c8);
        #pragma unroll
        for (int e = 0; e < 8; e++) qrow[w][il][c8 + e] = bf2f(qv[e]) * SCALE;
    }
    __syncthreads();

    float msq[4];
    #pragma unroll
    for (int r = 0; r < 4; r++) msq[r] = ms[i0 + quad * 4 + r];

    float mrow[4], lsum[4];
    #pragma unroll
    for (int r = 0; r < 4; r++) { mrow[r] = -3.0e38f; lsum[r] = 0.f; }
    f32x4 oacc0 = {0.f, 0.f, 0.f, 0.f}, oacc1 = {0.f, 0.f, 0.f, 0.f};
    float arel[8];
    #pragma unroll
    for (int e = 0; e < 8; e++) arel[e] = 0.f;

    int il = lane & 15, oct = lane >> 4;
    const short* relrow = relb + (((size_t)b * N1 + (i0 + il)) * N1) * HD + oct * 8;

    for (int jb = 0; jb < 8; jb++) {
        frag8 kb0 = *(const frag8*)&kf[2 * jb][lane][0];
        frag8 kb1 = *(const frag8*)&kf[2 * jb + 1][lane][0];
        f32x4 z = {0.f, 0.f, 0.f, 0.f};
        f32x4 s0 = __builtin_amdgcn_mfma_f32_16x16x32_bf16(qa, kb0, z, 0, 0, 0);
        f32x4 s1 = __builtin_amdgcn_mfma_f32_16x16x32_bf16(qa, kb1, z, 0, 0, 0);

        int j0 = jb * 32 + n;
        int j1 = j0 + 16;
        float mj0 = ms[j0], mj1 = ms[j1];

        #pragma unroll
        for (int r = 0; r < 4; r++) {
            int i = i0 + quad * 4 + r;
            const short* r0 = relb + (((size_t)b * N1 + i) * N1 + j0) * HD;
            const short* r1 = relb + (((size_t)b * N1 + i) * N1 + j1) * HD;
            float d0 = 0.f, d1 = 0.f;
            #pragma unroll
            for (int c8 = 0; c8 < 4; c8++) {
                frag8 ra = *(const frag8*)(r0 + c8 * 8);
                frag8 rb_ = *(const frag8*)(r1 + c8 * 8);
                const float* qp = &qrow[w][quad * 4 + r][c8 * 8];
                #pragma unroll
                for (int e = 0; e < 8; e++) {
                    float qv = qp[e];
                    d0 += qv * bf2f(ra[e]);
                    d1 += qv * bf2f(rb_[e]);
                }
            }
            float mi = msq[r];
            float b0 = (fmaxf(mi, mj0) < 0.f) ? 0.f : fminf(mi, mj0);
            float b1 = (fmaxf(mi, mj1) < 0.f) ? 0.f : fminf(mi, mj1);
            float v0 = s0[r] * SCALE + d0 + b0;
            float v1 = s1[r] * SCALE + d1 + b1;
            float rm = fmaxf(v0, v1);
            rm = fmaxf(rm, __shfl_xor(rm, 1));
            rm = fmaxf(rm, __shfl_xor(rm, 2));
            rm = fmaxf(rm, __shfl_xor(rm, 4));
            rm = fmaxf(rm, __shfl_xor(rm, 8));
            float mn = fmaxf(mrow[r], rm);
            float alpha = __expf(mrow[r] - mn);
            mrow[r] = mn;
            float p0 = __expf(v0 - mn);
            float p1 = __expf(v1 - mn);
            float ps = p0 + p1;
            ps += __shfl_xor(ps, 1);
            ps += __shfl_xor(ps, 2);
            ps += __shfl_xor(ps, 4);
            ps += __shfl_xor(ps, 8);
            lsum[r] = lsum[r] * alpha + ps;
            oacc0[r] *= alpha;
            oacc1[r] *= alpha;
            pbuf[w][quad * 4 + r][n]      = f2bf(p0);
            pbuf[w][quad * 4 + r][n + 16] = f2bf(p1);
            if (n == 0) alphas[w][quad * 4 + r] = alpha;
        }
        __builtin_amdgcn_wave_barrier();   // pbuf/alphas writes -> reads
        {
            float al = alphas[w][il];
            #pragma unroll
            for (int e = 0; e < 8; e++) arel[e] *= al;
            const short* rb2 = relrow + (size_t)(jb * 32) * HD;
            #pragma unroll 8
            for (int jj = 0; jj < 32; jj++) {
                float p = bf2f(pbuf[w][il][jj]);
                frag8 rv = *(const frag8*)(rb2 + (size_t)jj * HD);
                #pragma unroll
                for (int e = 0; e < 8; e++) arel[e] += p * bf2f(rv[e]);
            }
        }
        frag8 pa = *(const frag8*)&pbuf[w][n][quad * 8];
        frag8 vb0 = *(const frag8*)&vf[jb][0][lane][0];
        frag8 vb1 = *(const frag8*)&vf[jb][1][lane][0];
        oacc0 = __builtin_amdgcn_mfma_f32_16x16x32_bf16(pa, vb0, oacc0, 0, 0, 0);
        oacc1 = __builtin_amdgcn_mfma_f32_16x16x32_bf16(pa, vb1, oacc1, 0, 0, 0);
        __builtin_amdgcn_wave_barrier();   // pbuf reads -> next-iter writes
    }

    #pragma unroll
    for (int e = 0; e < 8; e++) orel[w][il][oct * 8 + e] = arel[e];
    __builtin_amdgcn_wave_barrier();       // orel writes -> reads (per-wave)

    #pragma unroll
    for (int r = 0; r < 4; r++) {
        int i = i0 + quad * 4 + r;
        float invl = 1.f / lsum[r];
        float o0 = (oacc0[r] + orel[w][quad * 4 + r][n])      * invl;
        float o1 = (oacc1[r] + orel[w][quad * 4 + r][16 + n]) * invl;
        ob[(rowB + i) * DIM + h * HD + n]      = f2bf(o0);
        ob[(rowB + i) * DIM + h * HD + 16 + n] = f2bf(o1);
    }
}

// ------------------------------------------------------------------
__global__ __launch_bounds__(256) void concat_kernel(
        const float* __restrict__ xa, const float* __restrict__ clsw,
        const float* __restrict__ mask, float* __restrict__ xb,
        float* __restrict__ m2) {
    int idx = blockIdx.x * 256 + threadIdx.x;
    const int total = BATCH * N2 * DIM;
    if (idx < total) {
        int c = idx % DIM;
        int tokb = idx / DIM;
        int p = tokb % N2, b = tokb / N2;
        xb[idx] = (p == 0) ? clsw[c] : xa[((size_t)(b * N1) + p - 1) * DIM + c];
    }
    if (idx < BATCH * N2) {
        int p = idx % N2, b = idx / N2;
        m2[idx] = (p == 0) ? 0.f : mask[b * N1 + p - 1];
    }
}

__global__ __launch_bounds__(64) void head_kernel(
        const float* __restrict__ xb, const float* __restrict__ ow,
        const float* __restrict__ obv, float* __restrict__ out) {
    int blk = blockIdx.x;
    int b = blk / 3, o = blk % 3;
    int lane = threadIdx.x;
    const float* xr = xb + (size_t)(b * N2) * DIM;
    const float* wr = ow + o * DIM;
    float s = 0.f;
    for (int c = lane; c < DIM; c += 64) s += xr[c] * wr[c];
    for (int off = 32; off; off >>= 1) s += __shfl_down(s, off, 64);
    if (!lane) out[blk] = s + obv[o];
}

// ------------------------------------------------------------------
extern "C" void kernel_launch(void* const* d_in, const int* in_sizes, int n_in,
                              void* d_out, int out_size, void* d_ws, size_t ws_size,
                              hipStream_t stream) {
    (void)in_sizes; (void)n_in; (void)out_size; (void)ws_size;
    const float* X       = (const float*)d_in[0];
    const float* X0      = (const float*)d_in[1];
    const float* MSK     = (const float*)d_in[2];
    const float* RW1     = (const float*)d_in[3];
    const float* RB1     = (const float*)d_in[4];
    const float* RWP     = (const float*)d_in[5];
    const float* RBP     = (const float*)d_in[6];
    const float* SW_LN1G = (const float*)d_in[7];
    const float* SW_LN1B = (const float*)d_in[8];
    const float* SW_LN2G = (const float*)d_in[9];
    const float* SW_LN2B = (const float*)d_in[10];
    const float* SW_WQ   = (const float*)d_in[11];
    const float* SW_WK   = (const float*)d_in[12];
    const float* SW_WV   = (const float*)d_in[13];
    const float* SW_WO   = (const float*)d_in[14];
    const float* SW_BO   = (const float*)d_in[15];
    const float* SW_W1   = (const float*)d_in[16];
    const float* SW_B1   = (const float*)d_in[17];
    const float* SW_W2   = (const float*)d_in[18];
    const float* SW_B2   = (const float*)d_in[19];
    const float* BL_LN1G = (const float*)d_in[20];
    const float* BL_LN1B = (const float*)d_in[21];
    const float* BL_LN2G = (const float*)d_in[22];
    const float* BL_LN2B = (const float*)d_in[23];
    const float* BL_WQ   = (const float*)d_in[24];
    const float* BL_WK   = (const float*)d_in[25];
    const float* BL_WV   = (const float*)d_in[26];
    const float* BL_WO   = (const float*)d_in[27];
    const float* BL_BO   = (const float*)d_in[28];
    const float* BL_W1   = (const float*)d_in[29];
    const float* BL_B1   = (const float*)d_in[30];
    const float* BL_W2   = (const float*)d_in[31];
    const float* BL_B2   = (const float*)d_in[32];
    const float* BL_G1   = (const float*)d_in[33];
    const float* BL_G2   = (const float*)d_in[34];
    const float* CLSW    = (const float*)d_in[35];
    const float* OUTW    = (const float*)d_in[36];
    const float* OUTB    = (const float*)d_in[37];

    const int T1 = BATCH * N1;   // 2048
    const int T2 = BATCH * N2;   // 2056
    const size_t RELSZ = (size_t)BATCH * N1 * N1 * HD;   // shorts

    short* rel = (short*)d_ws;
    float* xa  = (float*)(rel + RELSZ);
    float* xb  = xa + (size_t)T1 * DIM;
    float* m2  = xb + (size_t)T2 * DIM;
    short* sbase = (short*)(m2 + 2064);
    short* qkv  = sbase;
    short* ab   = qkv + (size_t)T2 * QP;
    short* hb   = ab  + (size_t)T2 * DIM;
    short* cw_qkv_sw = hb + (size_t)T2 * MLP_H;
    short* cw_qkv_bl = cw_qkv_sw + (size_t)4  * QP * DIM;
    short* cw_wo_sw  = cw_qkv_bl + (size_t)12 * QP * DIM;
    short* cw_wo_bl  = cw_wo_sw  + (size_t)4  * DIM * DIM;
    short* cw_w1_sw  = cw_wo_bl  + (size_t)12 * DIM * DIM;
    short* cw_w1_bl  = cw_w1_sw  + (size_t)4  * MLP_H * DIM;
    short* cw_w2_sw  = cw_w1_bl  + (size_t)12 * MLP_H * DIM;
    short* cw_w2_bl  = cw_w2_sw  + (size_t)4  * DIM * MLP_H;

    // ---- weight conversion ----
    conv_qkv_kernel<<<(4 * QP * DIM / 4 + 255) / 256, 256, 0, stream>>>(SW_WQ, SW_WK, SW_WV, cw_qkv_sw, 4);
    conv_qkv_kernel<<<(12 * QP * DIM / 4 + 255) / 256, 256, 0, stream>>>(BL_WQ, BL_WK, BL_WV, cw_qkv_bl, 12);
    conv_kernel<<<(4 * DIM * DIM / 4 + 255) / 256, 256, 0, stream>>>(SW_WO, cw_wo_sw, 4 * DIM * DIM);
    conv_kernel<<<(12 * DIM * DIM / 4 + 255) / 256, 256, 0, stream>>>(BL_WO, cw_wo_bl, 12 * DIM * DIM);
    conv_kernel<<<(4 * MLP_H * DIM / 4 + 255) / 256, 256, 0, stream>>>(SW_W1, cw_w1_sw, 4 * MLP_H * DIM);
    conv_kernel<<<(12 * MLP_H * DIM / 4 + 255) / 256, 256, 0, stream>>>(BL_W1, cw_w1_bl, 12 * MLP_H * DIM);
    conv_kernel<<<(4 * DIM * MLP_H / 4 + 255) / 256, 256, 0, stream>>>(SW_W2, cw_w2_sw, 4 * DIM * MLP_H);
    conv_kernel<<<(12 * DIM * MLP_H / 4 + 255) / 256, 256, 0, stream>>>(BL_W2, cw_w2_bl, 12 * DIM * MLP_H);

    rel_kernel<<<BATCH * N1 * N1 / 256, 256, 0, stream>>>(X0, RW1, RB1, RWP, RBP, rel);
    hipMemcpyAsync(xa, X, sizeof(float) * T1 * DIM, hipMemcpyDeviceToDevice, stream);

    // ---------------- phase 1: sw layers (N=256) ----------------
    dim3 gQ1(QP / 64, T1 / 64);
    dim3 gP1(DIM / 64, T1 / 64);
    dim3 gM1(MLP_H / 64, T1 / 64);
    dim3 gF1(4, HEADS, BATCH);
    for (int l = 0; l < 4; l++) {
        const short* wqkv = cw_qkv_sw + (size_t)l * QP * DIM;
        const short* wo = cw_wo_sw + (size_t)l * DIM * DIM;
        const short* w1 = cw_w1_sw + (size_t)l * MLP_H * DIM;
        const short* w2 = cw_w2_sw + (size_t)l * DIM * MLP_H;
        const float* bo = SW_BO + (size_t)l * DIM;
        const float* b1 = SW_B1 + (size_t)l * MLP_H;
        const float* b2 = SW_B2 + (size_t)l * DIM;

        gemm_ln_bf16_kernel<<<gQ1, 512, 0, stream>>>(
            xa, SW_LN1G + l * DIM, SW_LN1B + l * DIM, wqkv, nullptr, qkv, T1, QP, 0);
        if (l == 0)
            attn_rel_mfma_kernel<<<gF1, 256, 0, stream>>>(qkv, rel, MSK, ab);
        else
            attn_mfma_kernel<<<gF1, 256, 0, stream>>>(qkv, MSK, ab, N1);
        gemm_bf16_kernel<<<gP1, 512, 0, stream>>>(ab, wo, bo, xa, nullptr,
                                                  xa, nullptr, T1, DIM, DIM, 2);
        gemm_ln_bf16_kernel<<<gM1, 512, 0, stream>>>(
            xa, SW_LN2G + l * DIM, SW_LN2B + l * DIM, w1, b1, hb, T1, MLP_H, 1);
        gemm_bf16_kernel<<<gP1, 512, 0, stream>>>(hb, w2, b2, xa, nullptr,
                                                  xa, nullptr, T1, DIM, MLP_H, 2);
    }

    // ---------------- concat cls ----------------
    concat_kernel<<<(BATCH * N2 * DIM + 255) / 256, 256, 0, stream>>>(xa, CLSW, MSK, xb, m2);

    // ---------------- phase 2: bl layers (N=257) ----------------
    int MB2 = (T2 + 63) / 64;
    dim3 gQ2(QP / 64, MB2);
    dim3 gP2(DIM / 64, MB2);
    dim3 gM2(MLP_H / 64, MB2);
    dim3 gF2(5, HEADS, BATCH);
    for (int l = 0; l < 12; l++) {
        const short* wqkv = cw_qkv_bl + (size_t)l * QP * DIM;
        const short* wo = cw_wo_bl + (size_t)l * DIM * DIM;
        const short* w1 = cw_w1_bl + (size_t)l * MLP_H * DIM;
        const short* w2 = cw_w2_bl + (size_t)l * DIM * MLP_H;
        const float* bo = BL_BO + (size_t)l * DIM;
        const float* b1 = BL_B1 + (size_t)l * MLP_H;
        const float* b2 = BL_B2 + (size_t)l * DIM;
        const float* g1 = BL_G1 + (size_t)l * DIM;
        const float* g2 = BL_G2 + (size_t)l * DIM;

        gemm_ln_bf16_kernel<<<gQ2, 512, 0, stream>>>(
            xb, BL_LN1G + l * DIM, BL_LN1B + l * DIM, wqkv, nullptr, qkv, T2, QP, 0);
        attn_mfma_kernel<<<gF2, 256, 0, stream>>>(qkv, m2, ab, N2);
        gemm_bf16_kernel<<<gP2, 512, 0, stream>>>(ab, wo, bo, xb, g1,
                                                  xb, nullptr, T2, DIM, DIM, 2);
        gemm_ln_bf16_kernel<<<gM2, 512, 0, stream>>>(
            xb, BL_LN2G + l * DIM, BL_LN2B + l * DIM, w1, b1, hb, T2, MLP_H, 1);
        gemm_bf16_kernel<<<gP2, 512, 0, stream>>>(hb, w2, b2, xb, g2,
                                                  xb, nullptr, T2, DIM, MLP_H, 2);
    }

    // ---------------- head ----------------
    head_kernel<<<BATCH * 3, 64, 0, stream>>>(xb, OUTW, OUTB, (float*)d_out);
}